// Round 6
// baseline (285.677 us; speedup 1.0000x reference)
//
#include <hip/hip_runtime.h>

#define D 256

typedef unsigned short ushort_t;
typedef unsigned int uint_t;
typedef __attribute__((ext_vector_type(8))) short short8;
typedef __attribute__((ext_vector_type(4))) float floatx4;

static __device__ __forceinline__ ushort_t f2bf(float f) {
    union { float f; uint_t u; } c; c.f = f;
    uint_t r = (c.u + 0x7FFFu + ((c.u >> 16) & 1u)) >> 16;   // RN-even
    return (ushort_t)r;
}
static __device__ __forceinline__ float bf2f(ushort_t b) {
    union { uint_t u; float f; } c; c.u = ((uint_t)b) << 16;
    return c.f;
}
static __device__ __forceinline__ uint_t scale2(uint_t v, float s) {
    ushort_t lo = (ushort_t)(v & 0xFFFFu), hi = (ushort_t)(v >> 16);
    return (uint_t)f2bf(bf2f(lo) * s) | ((uint_t)f2bf(bf2f(hi) * s) << 16);
}

// async global->LDS DMA, 16B per lane, dest = uniform base + lane*16
static __device__ __forceinline__ void async16(const void* g, void* l) {
    __builtin_amdgcn_global_load_lds(
        (const __attribute__((address_space(1))) void*)g,
        (__attribute__((address_space(3))) void*)l, 16, 0, 0);
}

// ---------------------------------------------------------------------------
// Fused prep, 3 grid sections:
//  [0,degB):      rank[e] = atomicAdd(&deg[col[e]],1)  (histogram + edge rank)
//  [degB,+cvtB):  x -> bf16 (xh)
//  rest:          BT[j][k] j-major: k<256 Wself[k][j] | k<512 Wsrc | k<768 -Wdst
// ---------------------------------------------------------------------------
__global__ void prep_kernel(const int* __restrict__ col, int* __restrict__ deg,
                            int* __restrict__ rank,
                            const float* __restrict__ x, ushort_t* __restrict__ xh,
                            const float* __restrict__ Wself, const float* __restrict__ Wsrc,
                            const float* __restrict__ Wdst, ushort_t* __restrict__ BT,
                            int E, int total8, int degB, int cvtB) {
    int b = blockIdx.x;
    if (b < degB) {
        int e = b * 256 + threadIdx.x;
        if (e < E) rank[e] = atomicAdd(&deg[col[e]], 1);
    } else if (b < degB + cvtB) {
        int i = (b - degB) * 256 + threadIdx.x;
        if (i >= total8) return;
        float4 a = ((const float4*)x)[i * 2];
        float4 bb = ((const float4*)x)[i * 2 + 1];
        uint4 o;
        o.x = f2bf(a.x) | ((uint_t)f2bf(a.y) << 16);
        o.y = f2bf(a.z) | ((uint_t)f2bf(a.w) << 16);
        o.z = f2bf(bb.x) | ((uint_t)f2bf(bb.y) << 16);
        o.w = f2bf(bb.z) | ((uint_t)f2bf(bb.w) << 16);
        ((uint4*)xh)[i] = o;
    } else {
        int id = (b - degB - cvtB) * 256 + threadIdx.x;   // j*768+k
        if (id >= 256 * 768) return;
        int j = id / 768, k = id % 768;
        float v;
        if (k < 256)      v =  Wself[(size_t)k * 256 + j];
        else if (k < 512) v =  Wsrc [(size_t)(k - 256) * 256 + j];
        else              v = -Wdst [(size_t)(k - 512) * 256 + j];
        BT[id] = f2bf(v);
    }
}

// ---------------------------------------------------------------------------
// Scan phase A: per-block (1024 elems) local exclusive scan into off,
// block totals into partials. 256 threads x int4.
// ---------------------------------------------------------------------------
__global__ __launch_bounds__(256) void scanA(const int* __restrict__ deg,
                                             int* __restrict__ off,
                                             int* __restrict__ partials, int n4) {
    __shared__ int wtot[4];
    const int tid = threadIdx.x, lane = tid & 63, wid = tid >> 6;
    int i4 = blockIdx.x * 256 + tid;
    int4 v = (i4 < n4) ? ((const int4*)deg)[i4] : make_int4(0, 0, 0, 0);
    int s = v.x + v.y + v.z + v.w;
    int incl = s;
    #pragma unroll
    for (int st = 1; st < 64; st <<= 1) {
        int t = __shfl_up(incl, st, 64);
        if (lane >= st) incl += t;
    }
    if (lane == 63) wtot[wid] = incl;
    __syncthreads();
    int wbase = 0;
    #pragma unroll
    for (int w = 0; w < 4; ++w) if (w < wid) wbase += wtot[w];
    int excl = incl - s + wbase;
    if (i4 < n4) {
        int4 o;
        o.x = excl; o.y = o.x + v.x; o.z = o.y + v.y; o.w = o.z + v.z;
        ((int4*)off)[i4] = o;
    }
    if (tid == 0) partials[blockIdx.x] = wtot[0] + wtot[1] + wtot[2] + wtot[3];
}

// ---------------------------------------------------------------------------
// Scan phase C + Z-build, 2 grid sections:
//  [0,nblk):  off[i] += sum of earlier partials
//  rest:      Zh = deg * xh  (bf16), one thread per uint4 chunk (8 elems)
// ---------------------------------------------------------------------------
__global__ __launch_bounds__(256) void scanC(int* __restrict__ off,
                                             const int* __restrict__ partials, int n4,
                                             const ushort_t* __restrict__ xh,
                                             const int* __restrict__ deg,
                                             ushort_t* __restrict__ Zh,
                                             int nblk, int totalChunks) {
    const int tid = threadIdx.x;
    int b = blockIdx.x;
    if (b < nblk) {
        __shared__ int base_s;
        if (tid < 64) {
            int v = (tid < b) ? partials[tid] : 0;
            #pragma unroll
            for (int st = 32; st; st >>= 1) v += __shfl_down(v, st, 64);
            if (tid == 0) base_s = v;
        }
        __syncthreads();
        int base = base_s;
        int i4 = b * 256 + tid;
        if (i4 < n4) {
            int4 o = ((int4*)off)[i4];
            o.x += base; o.y += base; o.z += base; o.w += base;
            ((int4*)off)[i4] = o;
        }
    } else {
        int c = (b - nblk) * 256 + tid;          // chunk = 8 bf16 = uint4
        if (c >= totalChunks) return;
        int node = c >> 5;                        // 32 chunks per 256-elem row
        float s = (float)deg[node];
        uint4 v = ((const uint4*)xh)[c];
        uint4 o;
        o.x = scale2(v.x, s); o.y = scale2(v.y, s);
        o.z = scale2(v.z, s); o.w = scale2(v.w, s);
        ((uint4*)Zh)[c] = o;
    }
}

// ---------------------------------------------------------------------------
// Atomic-free bucket fill using precomputed ranks.
// ---------------------------------------------------------------------------
__global__ void fill_kernel(const int* __restrict__ row, const int* __restrict__ col,
                            const int* __restrict__ rank, const int* __restrict__ off,
                            int* __restrict__ bucket, int E) {
    int e = blockIdx.x * blockDim.x + threadIdx.x;
    if (e >= E) return;
    bucket[off[col[e]] + rank[e]] = row[e];
}

// ---------------------------------------------------------------------------
// Per-node gather-sum over bf16 rows, fp32 accum, bf16 out. One wave/node,
// lane = 4 consecutive bf16 (8B). 4-wide unroll for MLP.
// ---------------------------------------------------------------------------
__global__ __launch_bounds__(256) void segsum_kernel(const ushort_t* __restrict__ xh,
                                                     const int* __restrict__ off,
                                                     const int* __restrict__ deg,
                                                     const int* __restrict__ bucket,
                                                     ushort_t* __restrict__ Gh, int N) {
    int node = blockIdx.x * 4 + (threadIdx.x >> 6);
    int lane = threadIdx.x & 63;
    if (node >= N) return;
    int start = off[node];
    int cnt = deg[node];
    float a0 = 0.f, a1 = 0.f, a2 = 0.f, a3 = 0.f;
    int i = 0;
    for (; i + 4 <= cnt; i += 4) {
        int r0 = bucket[start + i];
        int r1 = bucket[start + i + 1];
        int r2 = bucket[start + i + 2];
        int r3 = bucket[start + i + 3];
        ushort4 v0 = ((const ushort4*)(xh + (size_t)r0 * D))[lane];
        ushort4 v1 = ((const ushort4*)(xh + (size_t)r1 * D))[lane];
        ushort4 v2 = ((const ushort4*)(xh + (size_t)r2 * D))[lane];
        ushort4 v3 = ((const ushort4*)(xh + (size_t)r3 * D))[lane];
        a0 += (bf2f(v0.x) + bf2f(v1.x)) + (bf2f(v2.x) + bf2f(v3.x));
        a1 += (bf2f(v0.y) + bf2f(v1.y)) + (bf2f(v2.y) + bf2f(v3.y));
        a2 += (bf2f(v0.z) + bf2f(v1.z)) + (bf2f(v2.z) + bf2f(v3.z));
        a3 += (bf2f(v0.w) + bf2f(v1.w)) + (bf2f(v2.w) + bf2f(v3.w));
    }
    for (; i < cnt; ++i) {
        int r0 = bucket[start + i];
        ushort4 v0 = ((const ushort4*)(xh + (size_t)r0 * D))[lane];
        a0 += bf2f(v0.x); a1 += bf2f(v0.y); a2 += bf2f(v0.z); a3 += bf2f(v0.w);
    }
    ushort4 o;
    o.x = f2bf(a0); o.y = f2bf(a1); o.z = f2bf(a2); o.w = f2bf(a3);
    ((ushort4*)(Gh + (size_t)node * D))[lane] = o;
}

// ---------------------------------------------------------------------------
// bf16 MFMA GEMM v3: BM=128, BN=256 (full width, grid.y=1), single accumulator.
//   A = [xh | Gh | Zh] (all DMA-staged), B = BT = [Wself; Wsrc; -Wdst].
//   out = acc + bself + deg*(bsrc-bdst)
// Double-buffered global_load_lds, ONE barrier per K-step: the DMA for kt+1
// is issued right after the barrier and flies during kt's 32 MFMAs.
// Fragment-major LDS [buf][group][lane][8]: conflict-free by construction.
// 4 waves 2x2 (m-half x n-half); per wave 4x8 16x16x32 tiles (128 acc VGPRs).
// ---------------------------------------------------------------------------
__global__ __launch_bounds__(256, 2) void mfma_gemm(
    const ushort_t* __restrict__ xh, const ushort_t* __restrict__ Gh,
    const ushort_t* __restrict__ Zh, const ushort_t* __restrict__ BT,
    const int* __restrict__ deg,
    const float* __restrict__ bsrc, const float* __restrict__ bdst,
    const float* __restrict__ bself, float* __restrict__ out, int N)
{
    __shared__ ushort_t As[2][8][64][8];    // 16 KB
    __shared__ ushort_t Bs[2][16][64][8];   // 32 KB

    const int tid = threadIdx.x;
    const int lane = tid & 63, wave = tid >> 6;
    const int quad = lane >> 4, l15 = lane & 15;
    const int mhalf = wave >> 1, nhalf = wave & 1;
    const int mbase = blockIdx.x * 128;

    // staging assignments: this wave fills A-groups ga0,ga1 and B-groups wave*4+0..3
    const int ga0 = wave * 2, ga1 = ga0 + 1;
    int ar0 = mbase + ga0 * 16 + l15; if (ar0 >= N) ar0 = N - 1;
    int ar1 = mbase + ga1 * 16 + l15; if (ar1 >= N) ar1 = N - 1;
    const size_t aoff0 = (size_t)ar0 * 256 + quad * 8;
    const size_t aoff1 = (size_t)ar1 * 256 + quad * 8;
    const ushort_t* bp0 = BT + (size_t)((wave * 4 + 0) * 16 + l15) * 768 + quad * 8;
    const ushort_t* bp1 = BT + (size_t)((wave * 4 + 1) * 16 + l15) * 768 + quad * 8;
    const ushort_t* bp2 = BT + (size_t)((wave * 4 + 2) * 16 + l15) * 768 + quad * 8;
    const ushort_t* bp3 = BT + (size_t)((wave * 4 + 3) * 16 + l15) * 768 + quad * 8;
    const ushort_t* Asrc_[3] = {xh, Gh, Zh};

    floatx4 acc[4][8] = {};

    // prologue: stage kt=0 into buffer 0
    async16(xh + aoff0, &As[0][ga0][0][0]);
    async16(xh + aoff1, &As[0][ga1][0][0]);
    async16(bp0, &Bs[0][wave * 4 + 0][0][0]);
    async16(bp1, &Bs[0][wave * 4 + 1][0][0]);
    async16(bp2, &Bs[0][wave * 4 + 2][0][0]);
    async16(bp3, &Bs[0][wave * 4 + 3][0][0]);

    for (int kt = 0; kt < 24; ++kt) {
        const int cur = kt & 1;
        __syncthreads();                       // drains DMA for kt, fences buf reuse
        if (kt < 23) {
            const int nk = kt + 1, nb = cur ^ 1;
            const ushort_t* s = Asrc_[nk >> 3];
            const int ka = (nk & 7) * 32;
            const int kb = nk * 32;
            async16(s + aoff0 + ka, &As[nb][ga0][0][0]);
            async16(s + aoff1 + ka, &As[nb][ga1][0][0]);
            async16(bp0 + kb, &Bs[nb][wave * 4 + 0][0][0]);
            async16(bp1 + kb, &Bs[nb][wave * 4 + 1][0][0]);
            async16(bp2 + kb, &Bs[nb][wave * 4 + 2][0][0]);
            async16(bp3 + kb, &Bs[nb][wave * 4 + 3][0][0]);
        }
        short8 af[4];
        #pragma unroll
        for (int im = 0; im < 4; ++im)
            af[im] = *(const short8*)(&As[cur][mhalf * 4 + im][lane][0]);
        #pragma unroll
        for (int h = 0; h < 2; ++h) {
            short8 bfr[4];
            #pragma unroll
            for (int in = 0; in < 4; ++in)
                bfr[in] = *(const short8*)(&Bs[cur][nhalf * 8 + h * 4 + in][lane][0]);
            #pragma unroll
            for (int im = 0; im < 4; ++im)
                #pragma unroll
                for (int in = 0; in < 4; ++in)
                    acc[im][h * 4 + in] = __builtin_amdgcn_mfma_f32_16x16x32_bf16(
                        af[im], bfr[in], acc[im][h * 4 + in], 0, 0, 0);
        }
    }

    // hoist deg for the 16 rows this thread writes
    float degv[4][4];
    #pragma unroll
    for (int im = 0; im < 4; ++im)
        #pragma unroll
        for (int r = 0; r < 4; ++r) {
            int gm = mbase + mhalf * 64 + im * 16 + quad * 4 + r;
            degv[im][r] = (gm < N) ? (float)deg[gm] : 0.f;
        }

    // C/D layout: col = lane&15, row = quad*4 + reg
    #pragma unroll
    for (int in = 0; in < 8; ++in) {
        int gn = nhalf * 128 + in * 16 + l15;
        float bs = bself[gn];
        float db = bsrc[gn] - bdst[gn];
        #pragma unroll
        for (int im = 0; im < 4; ++im) {
            #pragma unroll
            for (int r = 0; r < 4; ++r) {
                int gm = mbase + mhalf * 64 + im * 16 + quad * 4 + r;
                if (gm < N)
                    out[(size_t)gm * 256 + gn] = acc[im][in][r] + bs + degv[im][r] * db;
            }
        }
    }
}

extern "C" void kernel_launch(void* const* d_in, const int* in_sizes, int n_in,
                              void* d_out, int out_size, void* d_ws, size_t ws_size,
                              hipStream_t stream) {
    const float* x     = (const float*)d_in[0];
    const int*   eidx  = (const int*)d_in[1];
    const float* Wsrc  = (const float*)d_in[2];
    const float* bsrc  = (const float*)d_in[3];
    const float* Wdst  = (const float*)d_in[4];
    const float* bdst  = (const float*)d_in[5];
    const float* Wself = (const float*)d_in[6];
    const float* bself = (const float*)d_in[7];
    float* out = (float*)d_out;

    const int N = in_sizes[0] / D;       // 50000
    const int E = in_sizes[1] / 2;       // 800000
    const int* row = eidx;
    const int* col = eidx + E;

    // ws layout: xh | Gh | Zh | BT | deg | off | partials | bucket
    // rank[] (E ints) is ALIASED onto Gh: dead before segsum writes Gh.
    char* p = (char*)d_ws;
    ushort_t* xh  = (ushort_t*)p;        p += (size_t)N * D * sizeof(ushort_t);
    ushort_t* Gh  = (ushort_t*)p;        int* rank = (int*)p;
                                         p += (size_t)N * D * sizeof(ushort_t);
    ushort_t* Zh  = (ushort_t*)p;        p += (size_t)N * D * sizeof(ushort_t);
    ushort_t* BT  = (ushort_t*)p;        p += (size_t)768 * 256 * sizeof(ushort_t);
    int* deg      = (int*)p;             p += (size_t)N * sizeof(int);
    int* off      = (int*)p;             p += (size_t)N * sizeof(int);
    int* partials = (int*)p;             p += 64 * sizeof(int);
    int* bucket   = (int*)p;

    hipMemsetAsync(deg, 0, (size_t)N * sizeof(int), stream);

    const int total8 = N * D / 8;                 // 1,600,000
    const int degB = (E + 255) / 256;             // 3125
    const int cvtB = (total8 + 255) / 256;        // 6250
    const int btB  = (256 * 768 + 255) / 256;     // 768
    prep_kernel<<<degB + cvtB + btB, 256, 0, stream>>>(col, deg, rank, x, xh,
                                                       Wself, Wsrc, Wdst, BT,
                                                       E, total8, degB, cvtB);
    const int n4 = N / 4;                         // 12500
    const int nblk = (n4 + 255) / 256;            // 49 (<= 64 required)
    scanA<<<nblk, 256, 0, stream>>>(deg, off, partials, n4);
    scanC<<<nblk + cvtB, 256, 0, stream>>>(off, partials, n4, xh, deg, Zh, nblk, total8);
    fill_kernel<<<(E + 255) / 256, 256, 0, stream>>>(row, col, rank, off, bucket, E);
    segsum_kernel<<<(N + 3) / 4, 256, 0, stream>>>(xh, off, deg, bucket, Gh, N);

    mfma_gemm<<<dim3((N + 127) / 128), 256, 0, stream>>>(
        xh, Gh, Zh, BT, deg, bsrc, bdst, bself, out, N);
}